// Round 1
// baseline (289.391 us; speedup 1.0000x reference)
//
#include <hip/hip_runtime.h>

namespace {

constexpr int H = 1024;
constexpr int W = 1024;
constexpr int PLANE = H * W;
constexpr int CIN = 18;     // total input channels
constexpr int C = 8;        // filterable channels
constexpr int TX = 16;
constexpr int TY = 16;
constexpr int SW = TX + 6;  // 22 halo tile width
constexpr int SH = TY + 6;  // 22 halo tile height
constexpr int PSTR = 9;     // floats per LDS position: 8 channels + mask (odd -> conflict-free)
constexpr int ROWF = SW * PSTR;  // 198 floats per LDS row

template<bool INTERIOR>
__device__ __forceinline__ void run_tile(const float* __restrict__ inb,
                                         float* __restrict__ outb,
                                         float* lds,
                                         int gy0, int gx0)
{
    const int tx = threadIdx.x, ty = threadIdx.y;
    const int tid = ty * TX + tx;

    // ---- stage filterable channels: LDS layout [y][x][c], stride 9 ----
    constexpr int TOT = SH * C * SW;  // 3872
    for (int idx = tid; idx < TOT; idx += TX * TY) {
        int y = idx / (C * SW);
        int rem = idx - y * (C * SW);
        int c = rem / SW;
        int x = rem - c * SW;
        int gy = gy0 + y - 3;
        int gx = gx0 + x - 3;
        float v = 0.0f;
        if (INTERIOR || ((unsigned)gy < (unsigned)H && (unsigned)gx < (unsigned)W))
            v = inb[c * PLANE + gy * W + gx];
        lds[y * ROWF + x * PSTR + c] = v;
    }
    if (!INTERIOR) {
        // mask slot (1 inside image, 0 in padding)
        for (int idx = tid; idx < SH * SW; idx += TX * TY) {
            int y = idx / SW;
            int x = idx - y * SW;
            int gy = gy0 + y - 3;
            int gx = gx0 + x - 3;
            lds[y * ROWF + x * PSTR + C] =
                ((unsigned)gy < (unsigned)H && (unsigned)gx < (unsigned)W) ? 1.0f : 0.0f;
        }
    }
    __syncthreads();

    const int gy = gy0 + ty, gx = gx0 + tx;
    const int pofs = gy * W + gx;
    const float* lp = lds + ty * ROWF + tx * PSTR;  // window origin for this pixel

    // center values (position +3,+3 in the window)
    float f[C];
#pragma unroll
    for (int c = 0; c < C; ++c) f[c] = lp[3 * ROWF + 3 * PSTR + c];

    // per-pixel params: rp_c = -(p_c^2), sx = -(px^2), sy = -(py^2)
    float rp[C];
#pragma unroll
    for (int c = 0; c < C; ++c) {
        float p = inb[(C + c) * PLANE + pofs];
        rp[c] = -(p * p);
    }
    float px_ = inb[16 * PLANE + pofs];
    float py_ = inb[17 * PLANE + pofs];
    const float sx = -(px_ * px_);
    const float sy = -(py_ * py_);

    float acc0 = 0.f, acc1 = 0.f, acc2 = 0.f, ws = 0.f;
#pragma unroll
    for (int i = 0; i < 7; ++i) {
        const float ey = sy * (float)((i - 3) * (i - 3));
#pragma unroll
        for (int j = 0; j < 7; ++j) {
            const float* q = lp + (i * ROWF + j * PSTR);
            float logw = fmaf(sx, (float)((j - 3) * (j - 3)), ey);
            float fn0 = q[0], fn1 = q[1], fn2 = q[2], fn3 = q[3];
            float fn4 = q[4], fn5 = q[5], fn6 = q[6], fn7 = q[7];
            float d;
            d = fn0 - f[0]; logw = fmaf(rp[0] * d, d, logw);
            d = fn1 - f[1]; logw = fmaf(rp[1] * d, d, logw);
            d = fn2 - f[2]; logw = fmaf(rp[2] * d, d, logw);
            d = fn3 - f[3]; logw = fmaf(rp[3] * d, d, logw);
            d = fn4 - f[4]; logw = fmaf(rp[4] * d, d, logw);
            d = fn5 - f[5]; logw = fmaf(rp[5] * d, d, logw);
            d = fn6 - f[6]; logw = fmaf(rp[6] * d, d, logw);
            d = fn7 - f[7]; logw = fmaf(rp[7] * d, d, logw);
            float w = __expf(logw);
            if (!INTERIOR) w *= q[C];  // padding mask
            ws += w;
            acc0 = fmaf(w, fn0, acc0);
            acc1 = fmaf(w, fn1, acc1);
            acc2 = fmaf(w, fn2, acc2);
        }
    }
    const float inv = 1.0f / ws;
    outb[pofs]             = acc0 * inv;
    outb[PLANE + pofs]     = acc1 * inv;
    outb[2 * PLANE + pofs] = acc2 * inv;
}

__global__ __launch_bounds__(TX * TY, 4) void bilateral_kernel(const float* __restrict__ in,
                                                               float* __restrict__ out)
{
    __shared__ float lds[SH * ROWF];
    const int b = blockIdx.z;
    const int gx0 = blockIdx.x * TX;
    const int gy0 = blockIdx.y * TY;
    const float* inb = in + (size_t)b * CIN * PLANE;
    float* outb = out + (size_t)b * 3 * PLANE;

    // block-uniform interior test (no mask / bounds work needed)
    const bool interior = (gx0 >= 3) && (gx0 + TX + 3 <= W) &&
                          (gy0 >= 3) && (gy0 + TY + 3 <= H);
    if (interior)
        run_tile<true>(inb, outb, lds, gy0, gx0);
    else
        run_tile<false>(inb, outb, lds, gy0, gx0);
}

} // namespace

extern "C" void kernel_launch(void* const* d_in, const int* in_sizes, int n_in,
                              void* d_out, int out_size, void* d_ws, size_t ws_size,
                              hipStream_t stream)
{
    const float* in = (const float*)d_in[0];
    float* out = (float*)d_out;
    dim3 grid(W / TX, H / TY, 2);
    dim3 block(TX, TY);
    hipLaunchKernelGGL(bilateral_kernel, grid, block, 0, stream, in, out);
}

// Round 2
// 254.905 us; speedup vs baseline: 1.1353x; 1.1353x over previous
//
#include <hip/hip_runtime.h>

namespace {

constexpr int H = 1024;
constexpr int W = 1024;
constexpr int PLANE = H * W;
constexpr int CIN = 18;     // total input channels
constexpr int C = 8;        // filterable channels
constexpr int TX = 16;
constexpr int TY = 16;
constexpr int SW = TX + 6;  // 22 halo tile width
constexpr int SH = TY + 6;  // 22 halo tile height
constexpr int NPOS = SW * SH;  // 484 positions
constexpr float LOG2E = 1.44269504088896340736f;

typedef _Float16 half2_t __attribute__((ext_vector_type(2)));
typedef _Float16 half8_t __attribute__((ext_vector_type(8)));

__device__ __forceinline__ float dot2acc(half2_t a, half2_t b, float c) {
#if defined(__has_builtin)
#if __has_builtin(__builtin_amdgcn_fdot2)
    return __builtin_amdgcn_fdot2(a, b, c, false);
#else
    return fmaf((float)a[0], (float)b[0], fmaf((float)a[1], (float)b[1], c));
#endif
#else
    return fmaf((float)a[0], (float)b[0], fmaf((float)a[1], (float)b[1], c));
#endif
}

__device__ __forceinline__ float fast_exp2(float x) {
#if defined(__has_builtin)
#if __has_builtin(__builtin_amdgcn_exp2f)
    return __builtin_amdgcn_exp2f(x);
#else
    return exp2f(x);
#endif
#else
    return exp2f(x);
#endif
}

template<bool INTERIOR>
__device__ __forceinline__ void run_tile(const float* __restrict__ inb,
                                         float* __restrict__ outb,
                                         half8_t* __restrict__ tile,
                                         float* __restrict__ msk,
                                         int gy0, int gx0)
{
    const int tx = threadIdx.x, ty = threadIdx.y;
    const int tid = ty * TX + tx;

    // ---- stage: one 16B packed-f16 record per halo position ----
    for (int idx = tid; idx < NPOS; idx += TX * TY) {
        int y = idx / SW;
        int x = idx - y * SW;
        int gy = gy0 + y - 3;
        int gx = gx0 + x - 3;
        half8_t hv;
        if (INTERIOR || ((unsigned)gy < (unsigned)H && (unsigned)gx < (unsigned)W)) {
            const float* p = inb + gy * W + gx;
#pragma unroll
            for (int c = 0; c < C; ++c) hv[c] = (_Float16)p[c * PLANE];
            if (!INTERIOR) msk[idx] = 1.0f;
        } else {
#pragma unroll
            for (int c = 0; c < C; ++c) hv[c] = (_Float16)0.0f;
            msk[idx] = 0.0f;
        }
        tile[idx] = hv;
    }
    __syncthreads();

    const int gy = gy0 + ty, gx = gx0 + tx;
    const int pofs = gy * W + gx;
    const half8_t* lp = tile + ty * SW + tx;  // window origin for this pixel

    // center values (position +3,+3 in window), f16 (so d==0 exactly at center)
    const half8_t fc = lp[3 * SW + 3];

    // per-pixel params, log2e folded in: rp_c = -(p_c^2)*log2e, etc.
    half2_t rp01, rp23, rp45, rp67;
    {
        const float* pp = inb + C * PLANE + pofs;
        float r[C];
#pragma unroll
        for (int c = 0; c < C; ++c) {
            float p = pp[c * PLANE];
            r[c] = -(p * p) * LOG2E;
        }
        rp01 = half2_t{(_Float16)r[0], (_Float16)r[1]};
        rp23 = half2_t{(_Float16)r[2], (_Float16)r[3]};
        rp45 = half2_t{(_Float16)r[4], (_Float16)r[5]};
        rp67 = half2_t{(_Float16)r[6], (_Float16)r[7]};
    }
    float px_ = inb[16 * PLANE + pofs];
    float py_ = inb[17 * PLANE + pofs];
    const float sx = -(px_ * px_) * LOG2E;
    const float sy = -(py_ * py_) * LOG2E;

    // spatial term per column, precomputed
    float exj[7];
#pragma unroll
    for (int j = 0; j < 7; ++j) exj[j] = sx * (float)((j - 3) * (j - 3));

    float acc0 = 0.f, acc1 = 0.f, acc2 = 0.f, ws = 0.f;
#pragma unroll
    for (int i = 0; i < 7; ++i) {
        const float ey = sy * (float)((i - 3) * (i - 3));
        const half8_t* row = lp + i * SW;
        const float* mrow = msk + (ty + i) * SW + tx;
#pragma unroll
        for (int j = 0; j < 7; ++j) {
            half8_t q = row[j];                 // one ds_read_b128
            half8_t d = q - fc;                 // 4x v_pk_add_f16
            half8_t dd = d * d;                 // 4x v_pk_mul_f16
            float logw = exj[j] + ey;
            logw = dot2acc(__builtin_shufflevector(dd, dd, 0, 1), rp01, logw);
            logw = dot2acc(__builtin_shufflevector(dd, dd, 2, 3), rp23, logw);
            logw = dot2acc(__builtin_shufflevector(dd, dd, 4, 5), rp45, logw);
            logw = dot2acc(__builtin_shufflevector(dd, dd, 6, 7), rp67, logw);
            float w = fast_exp2(logw);
            if (!INTERIOR) w *= mrow[j];        // padding mask
            ws += w;
            acc0 = fmaf(w, (float)q[0], acc0);  // v_fma_mix_f32
            acc1 = fmaf(w, (float)q[1], acc1);
            acc2 = fmaf(w, (float)q[2], acc2);
        }
    }
    const float inv = 1.0f / ws;
    outb[pofs]             = acc0 * inv;
    outb[PLANE + pofs]     = acc1 * inv;
    outb[2 * PLANE + pofs] = acc2 * inv;
}

__global__ __launch_bounds__(TX * TY, 4) void bilateral_kernel(const float* __restrict__ in,
                                                               float* __restrict__ out)
{
    __shared__ __align__(16) half8_t tile[NPOS];
    __shared__ float msk[NPOS];
    const int b = blockIdx.z;
    const int gx0 = blockIdx.x * TX;
    const int gy0 = blockIdx.y * TY;
    const float* inb = in + (size_t)b * CIN * PLANE;
    float* outb = out + (size_t)b * 3 * PLANE;

    const bool interior = (gx0 >= 3) && (gx0 + TX + 3 <= W) &&
                          (gy0 >= 3) && (gy0 + TY + 3 <= H);
    if (interior)
        run_tile<true>(inb, outb, tile, msk, gy0, gx0);
    else
        run_tile<false>(inb, outb, tile, msk, gy0, gx0);
}

} // namespace

extern "C" void kernel_launch(void* const* d_in, const int* in_sizes, int n_in,
                              void* d_out, int out_size, void* d_ws, size_t ws_size,
                              hipStream_t stream)
{
    const float* in = (const float*)d_in[0];
    float* out = (float*)d_out;
    dim3 grid(W / TX, H / TY, 2);
    dim3 block(TX, TY);
    hipLaunchKernelGGL(bilateral_kernel, grid, block, 0, stream, in, out);
}